// Round 4
// baseline (1887.894 us; speedup 1.0000x reference)
//
#include <hip/hip_runtime.h>

#define DIM 1024
#define NROWS 65536
#define PICK 12

// -------------------------------------------------------------------------
// ws layout (floats):
//   0      NK  [12][1024]
//   12288  Qr  [12][1024]
//   24576  Mt  [12][1024]   (zeroed, atomic-accumulated, TRANSPOSED: [j][e])
//   36864  Rt  [12][1024]   (zeroed, atomic-accumulated, TRANSPOSED: [j][e])
//   49152  c0  [12] (pad16, zeroed)
//   49168  c1  [12] (pad16, zeroed)
//   49184  cand_v [768]
//   49952  cand_i [768] (int)
//   50720  top_idx [12] (int, pad16)
//   50736  maxv [65536]
// -------------------------------------------------------------------------

// out[j][d] = sum_e emb[idx[j]][e] * W[d][e] + b[d]      (12 x 1024)
__global__ void __launch_bounds__(256)
rows12_kernel(const float* __restrict__ emb, const float* __restrict__ W,
              const float* __restrict__ b, const int* __restrict__ idx,
              float* __restrict__ out) {
    int d = blockIdx.x;
    int t = threadIdx.x;
    int lane = t & 63;
    int q = t >> 6;
    int e0 = q * 256 + lane * 4;
    float4 w4 = *(const float4*)&W[(size_t)d * DIM + e0];
    float part[PICK];
#pragma unroll
    for (int j = 0; j < PICK; ++j) {
        int r = idx[j];
        float4 e4 = *(const float4*)&emb[(size_t)r * DIM + e0];
        part[j] = w4.x * e4.x + w4.y * e4.y + w4.z * e4.z + w4.w * e4.w;
    }
#pragma unroll
    for (int j = 0; j < PICK; ++j) {
        float v = part[j];
        for (int s = 32; s > 0; s >>= 1) v += __shfl_down(v, s, 64);
        part[j] = v;
    }
    __shared__ float red[4][PICK];
    if (lane == 0) {
#pragma unroll
        for (int j = 0; j < PICK; ++j) red[q][j] = part[j];
    }
    __syncthreads();
    if (t < PICK) {
        float s = red[0][t] + red[1][t] + red[2][t] + red[3][t] + b[d];
        out[t * DIM + d] = s;
    }
}

// TRANSPOSED output: out[j][e] += sum_d W[d][e] * V[j][d];  cvec[j] += sum_d b[d]*V[j][d]
__global__ void __launch_bounds__(256)
colmat_kernel(const float* __restrict__ W, const float* __restrict__ V,
              const float* __restrict__ b, float* __restrict__ out,
              float* __restrict__ cvec) {
    int blk = blockIdx.x;
    int t = threadIdx.x;
    if (blk == 128) {
        float part[PICK];
#pragma unroll
        for (int j = 0; j < PICK; ++j) part[j] = 0.f;
        for (int k = 0; k < 4; ++k) {
            int d = t + k * 256;
            float bv = b[d];
#pragma unroll
            for (int j = 0; j < PICK; ++j) part[j] += bv * V[j * DIM + d];
        }
#pragma unroll
        for (int j = 0; j < PICK; ++j) {
            float v = part[j];
            for (int s = 32; s > 0; s >>= 1) v += __shfl_down(v, s, 64);
            if ((t & 63) == 0) atomicAdd(&cvec[j], v);
        }
        return;
    }
    int eg = blk & 3;
    int dg = blk >> 2;
    int e = eg * 256 + t;
    int d0 = dg * 32;
    __shared__ float Vs[PICK][32];
    for (int i = t; i < PICK * 32; i += 256) {
        int j = i >> 5, dd = i & 31;
        Vs[j][dd] = V[j * DIM + d0 + dd];
    }
    __syncthreads();
    float acc[PICK];
#pragma unroll
    for (int j = 0; j < PICK; ++j) acc[j] = 0.f;
    for (int dd = 0; dd < 32; ++dd) {
        float w = W[(size_t)(d0 + dd) * DIM + e];
#pragma unroll
        for (int j = 0; j < PICK; ++j) acc[j] += w * Vs[j][dd];
    }
#pragma unroll
    for (int j = 0; j < PICK; ++j) atomicAdd(&out[j * DIM + e], acc[j]);
}

// -------------------------------------------------------------------------
// pass kernels (R9): LDS-traffic fix.
// R8 post-mortem: removing the per-PG barrier changed NOTHING (555->555),
// so the drain wasn't the limiter. Remaining suspect with arithmetic: the
// 2-row PG re-read the same 48 KB of sMt fragments per 2 rows -> LDS:HBM
// byte ratio 6:1 -> ~61 B/cyc LDS needed at HBM pace + ~8 B/cyc epilogue
// ~= 85-90% of the measured 85 B/cyc ds_read_b128 ceiling. The LDS pipe,
// not HBM, paced the loop (VALU 9%, both mem pipes queued).
// Fix: chunk-outer loop over an 8-row register tile. m4[12] loaded once
// per 256-col chunk and applied to 8 rows -> LDS m-traffic / 4 (ratio
// 1.5:1, ~22 B/cyc total). Same FMA count, same summation order
// (chunk-major per quad-lane -> bit-identical numerics), same scr
// epilogue per 2 rows, same 8x1KB wave-contiguous ping-pong prefetch.
// VGPR ~220 (bufA/B 64 + m4 48 + acc 96) < 256 at 2 blocks/CU.
// -------------------------------------------------------------------------

// one 256-col chunk: prefetch NBUF (8 rows, chunk PF_CHUNK of rows PF_ROW..),
// load m4 for chunk CC, FMA CBUF into acc[8][12]
#define CHUNK(CBUF, NBUF, CC, PF_ROW, PF_CHUNK)                               \
  {                                                                           \
    _Pragma("unroll") for (int r = 0; r < 8; ++r)                             \
      NBUF[r] = *(const float4*)(emb + (size_t)((PF_ROW) + r) * DIM +         \
                                 (PF_CHUNK) * 256 + l * 4);                   \
    float4 m4[12];                                                            \
    _Pragma("unroll") for (int j = 0; j < 12; ++j)                            \
      m4[j] = *(const float4*)&sMt[j * DIM + (CC) * 256 + l * 4];             \
    _Pragma("unroll") for (int r = 0; r < 8; ++r) {                           \
      float f0 = CBUF[r].x, f1 = CBUF[r].y, f2 = CBUF[r].z, f3 = CBUF[r].w;   \
      _Pragma("unroll") for (int j = 0; j < 12; ++j)                          \
        acc[r][j] += f0 * m4[j].x + f1 * m4[j].y + f2 * m4[j].z +             \
                     f3 * m4[j].w;                                            \
    }                                                                         \
  }

// epilogue for rows R0, R0+1 (acc indices): quad butterfly -> scr -> sum16
// -> +bias -> max butterfly. Even lanes end with row R0 max, odd lanes R0+1.
#define EPI(R0, PAR, SINK)                                                    \
  {                                                                           \
    float a0[PICK], a1[PICK];                                                 \
    _Pragma("unroll") for (int j = 0; j < PICK; ++j) {                        \
      float v0 = acc[R0][j], v1 = acc[R0 + 1][j];                             \
      v0 += __shfl_xor(v0, 1, 64); v0 += __shfl_xor(v0, 2, 64);               \
      v1 += __shfl_xor(v1, 1, 64); v1 += __shfl_xor(v1, 2, 64);               \
      a0[j] = v0; a1[j] = v1;                                                 \
    }                                                                         \
    if ((l & 3) == 0) {                                                       \
      _Pragma("unroll") for (int jh = 0; jh < 6; ++jh) {                      \
        float4 b4 = {a0[2 * jh], a1[2 * jh], a0[2 * jh + 1], a1[2 * jh + 1]}; \
        *(float4*)&scr[PAR][w][q][jh * 4] = b4;                               \
      }                                                                       \
    }                                                                         \
    asm volatile("s_waitcnt lgkmcnt(0)" ::: "memory");                        \
    float sum = 0.f;                                                          \
    _Pragma("unroll") for (int qq = 0; qq < 16; ++qq)                         \
      sum += scr[PAR][w][qq][pidx];                                           \
    float vmax = (p < 24) ? sum + cb : -3e38f;                                \
    _Pragma("unroll") for (int mm = 2; mm <= 16; mm <<= 1)                    \
      vmax = fmaxf(vmax, __shfl_xor(vmax, mm, 64));                           \
    if (p < 2) SINK = vmax;                                                   \
  }

__global__ void __launch_bounds__(256, 2)
pass1_kernel(const float* __restrict__ emb, const float* __restrict__ Mt,
             const float* __restrict__ c0, float* __restrict__ maxv) {
    __shared__ __align__(16) float sMt[PICK * DIM];        // 48 KB
    __shared__ __align__(16) float scr[2][4][16][28];      // 14 KB
    int t = threadIdx.x;
    for (int i = t; i < PICK * DIM / 4; i += 256)
        ((float4*)sMt)[i] = ((const float4*)Mt)[i];
    __syncthreads();

    int l = t & 63, w = t >> 6;
    int q = l >> 2;
    int p = l;                       // pair id: p = j*2 + r for p < 24
    int pidx = (p < 24) ? p : 0;     // broadcast-read for idle lanes
    float cb = (p < 24) ? c0[p >> 1] : 0.f;
    size_t wrow = (size_t)blockIdx.x * 128 + (size_t)w * 32;

    float4 bufA[8], bufB[8];
#pragma unroll
    for (int r = 0; r < 8; ++r)
        bufA[r] = *(const float4*)(emb + (wrow + r) * DIM + l * 4);

    for (int tile = 0; tile < 4; ++tile) {
        size_t trow = wrow + (size_t)tile * 8;
        size_t ntrow = wrow + (size_t)((tile < 3) ? tile + 1 : 3) * 8;
        float acc[8][PICK];
#pragma unroll
        for (int r = 0; r < 8; ++r)
#pragma unroll
            for (int j = 0; j < PICK; ++j) acc[r][j] = 0.f;

        CHUNK(bufA, bufB, 0, trow, 1);
        CHUNK(bufB, bufA, 1, trow, 2);
        CHUNK(bufA, bufB, 2, trow, 3);
        CHUNK(bufB, bufA, 3, ntrow, 0);

        EPI(0, 0, maxv[trow + 0 + p]);
        EPI(2, 1, maxv[trow + 2 + p]);
        EPI(4, 0, maxv[trow + 4 + p]);
        EPI(6, 1, maxv[trow + 6 + p]);
    }
}

__global__ void __launch_bounds__(256, 2)
pass2_kernel(const float* __restrict__ emb, const float* __restrict__ Rt,
             const float* __restrict__ c1, float* __restrict__ out) {
    __shared__ __align__(16) float sMt[PICK * DIM];        // 48 KB
    __shared__ __align__(16) float scr[2][4][16][28];      // 14 KB
    __shared__ float pooled[128];
    int t = threadIdx.x;
    for (int i = t; i < PICK * DIM / 4; i += 256)
        ((float4*)sMt)[i] = ((const float4*)Rt)[i];
    __syncthreads();

    int l = t & 63, w = t >> 6;
    int q = l >> 2;
    int p = l;
    int pidx = (p < 24) ? p : 0;
    float cb = (p < 24) ? c1[p >> 1] : 0.f;
    size_t bbase = (size_t)blockIdx.x * 128;
    size_t wrow = bbase + (size_t)w * 32;

    float4 bufA[8], bufB[8];
#pragma unroll
    for (int r = 0; r < 8; ++r)
        bufA[r] = *(const float4*)(emb + (wrow + r) * DIM + l * 4);

    for (int tile = 0; tile < 4; ++tile) {
        size_t trow = wrow + (size_t)tile * 8;
        size_t ntrow = wrow + (size_t)((tile < 3) ? tile + 1 : 3) * 8;
        float acc[8][PICK];
#pragma unroll
        for (int r = 0; r < 8; ++r)
#pragma unroll
            for (int j = 0; j < PICK; ++j) acc[r][j] = 0.f;

        CHUNK(bufA, bufB, 0, trow, 1);
        CHUNK(bufB, bufA, 1, trow, 2);
        CHUNK(bufA, bufB, 2, trow, 3);
        CHUNK(bufB, bufA, 3, ntrow, 0);

        EPI(0, 0, pooled[w * 32 + tile * 8 + 0 + p]);
        EPI(2, 1, pooled[w * 32 + tile * 8 + 2 + p]);
        EPI(4, 0, pooled[w * 32 + tile * 8 + 4 + p]);
        EPI(6, 1, pooled[w * 32 + tile * 8 + 6 + p]);
    }
    __syncthreads();

    // phase B: thread t owns cols t*4..t*4+3; wave reads are 1 KB contiguous.
    // Re-walk the block's 128 rows (L2/L3-hot from phase A).
    const float* tp = emb + bbase * DIM + t * 4;
    float4 o = {0.f, 0.f, 0.f, 0.f};
#pragma unroll 8
    for (int r = 0; r < 128; ++r) {
        float pv = pooled[r];
        float4 v = *(const float4*)(tp + (size_t)r * DIM);
        o.x += pv * v.x; o.y += pv * v.y; o.z += pv * v.z; o.w += pv * v.w;
    }
    atomicAdd(&out[t * 4 + 0], o.x);
    atomicAdd(&out[t * 4 + 1], o.y);
    atomicAdd(&out[t * 4 + 2], o.z);
    atomicAdd(&out[t * 4 + 3], o.w);
}

// local top-12 of each 1024-chunk of maxv, single wave, register-resident,
// barrier-free: element q*64+t is only ever scanned AND cleared by lane t.
__global__ void __launch_bounds__(64)
top12_local(const float* __restrict__ maxv, float* __restrict__ cand_v,
            int* __restrict__ cand_i) {
    int t = threadIdx.x;
    int base = blockIdx.x * 1024;
    float lv[16];
#pragma unroll
    for (int q = 0; q < 16; ++q) lv[q] = maxv[base + q * 64 + t];
    for (int k = 0; k < PICK; ++k) {
        float bv = -3e38f; int bi = 0x7fffffff;
#pragma unroll
        for (int q = 0; q < 16; ++q) {
            int ii = base + q * 64 + t;
            float v = lv[q];
            if (v > bv || (v == bv && ii < bi)) { bv = v; bi = ii; }
        }
#pragma unroll
        for (int sft = 1; sft < 64; sft <<= 1) {
            float ov = __shfl_xor(bv, sft, 64);
            int oi = __shfl_xor(bi, sft, 64);
            if (ov > bv || (ov == bv && oi < bi)) { bv = ov; bi = oi; }
        }
        if (t == 0) {
            cand_v[blockIdx.x * PICK + k] = bv;
            cand_i[blockIdx.x * PICK + k] = bi;
        }
#pragma unroll
        for (int q = 0; q < 16; ++q)
            if (base + q * 64 + t == bi) lv[q] = -3e38f;
    }
}

// merge 768 candidates -> global top-12 indices; single wave, 12 regs/lane.
__global__ void __launch_bounds__(64)
top12_merge(const float* __restrict__ cand_v, const int* __restrict__ cand_i,
            int* __restrict__ top_idx) {
    int t = threadIdx.x;
    float lv[12]; int li[12];
#pragma unroll
    for (int q = 0; q < 12; ++q) {
        lv[q] = cand_v[q * 64 + t];
        li[q] = cand_i[q * 64 + t];
    }
    for (int k = 0; k < PICK; ++k) {
        float bv = -3e38f; int bi = 0x7fffffff; int bs = -1;
#pragma unroll
        for (int q = 0; q < 12; ++q) {
            if (lv[q] > bv || (lv[q] == bv && li[q] < bi)) {
                bv = lv[q]; bi = li[q]; bs = q * 64 + t;
            }
        }
#pragma unroll
        for (int sft = 1; sft < 64; sft <<= 1) {
            float ov = __shfl_xor(bv, sft, 64);
            int oi = __shfl_xor(bi, sft, 64);
            int os = __shfl_xor(bs, sft, 64);
            if (ov > bv || (ov == bv && oi < bi)) { bv = ov; bi = oi; bs = os; }
        }
        if (t == 0) top_idx[k] = bi;
#pragma unroll
        for (int q = 0; q < 12; ++q)
            if (q * 64 + t == bs) lv[q] = -3e38f;
    }
}

extern "C" void kernel_launch(void* const* d_in, const int* in_sizes, int n_in,
                              void* d_out, int out_size, void* d_ws, size_t ws_size,
                              hipStream_t stream) {
    const float* emb = (const float*)d_in[0];
    const float* Wq  = (const float*)d_in[1];
    const float* bq  = (const float*)d_in[2];
    const float* Wk  = (const float*)d_in[3];
    const float* bk  = (const float*)d_in[4];
    const int* indices = (const int*)d_in[5];
    float* out = (float*)d_out;
    float* ws = (float*)d_ws;

    float* NK      = ws;             // 12288
    float* Qr      = ws + 12288;     // 12288
    float* Mt      = ws + 24576;     // 12288 (zeroed, transposed [12][1024])
    float* Rt      = ws + 36864;     // 12288 (zeroed, transposed [12][1024])
    float* c0      = ws + 49152;     // 16    (zeroed)
    float* c1      = ws + 49168;     // 16    (zeroed)
    float* cand_v  = ws + 49184;     // 768
    int*   cand_i  = (int*)(ws + 49952);   // 768
    int*   top_idx = (int*)(ws + 50720);   // 16
    float* maxv    = ws + 50736;     // 65536

    hipMemsetAsync(Mt, 0, (size_t)(12288 * 2 + 32) * sizeof(float), stream);
    hipMemsetAsync(out, 0, DIM * sizeof(float), stream);

    rows12_kernel<<<1024, 256, 0, stream>>>(emb, Wk, bk, indices, NK);
    colmat_kernel<<<129, 256, 0, stream>>>(Wq, NK, bq, Mt, c0);
    pass1_kernel<<<512, 256, 0, stream>>>(emb, Mt, c0, maxv);
    top12_local<<<64, 64, 0, stream>>>(maxv, cand_v, cand_i);
    top12_merge<<<1, 64, 0, stream>>>(cand_v, cand_i, top_idx);
    rows12_kernel<<<1024, 256, 0, stream>>>(emb, Wq, bq, top_idx, Qr);
    colmat_kernel<<<129, 256, 0, stream>>>(Wk, Qr, bk, Rt, c1);
    pass2_kernel<<<512, 256, 0, stream>>>(emb, Rt, c1, out);
}

// Round 5
// 794.155 us; speedup vs baseline: 2.3772x; 2.3772x over previous
//
#include <hip/hip_runtime.h>

#define DIM 1024
#define NROWS 65536
#define PICK 12

// -------------------------------------------------------------------------
// ws layout (floats):
//   0      NK  [12][1024]
//   12288  Qr  [12][1024]
//   24576  Mt  [12][1024]   (zeroed, atomic-accumulated, TRANSPOSED: [j][e])
//   36864  Rt  [12][1024]   (zeroed, atomic-accumulated, TRANSPOSED: [j][e])
//   49152  c0  [12] (pad16, zeroed)
//   49168  c1  [12] (pad16, zeroed)
//   49184  cand_v [768]
//   49952  cand_i [768] (int)
//   50720  top_idx [12] (int, pad16)
//   50736  maxv [65536]
// -------------------------------------------------------------------------

// out[j][d] = sum_e emb[idx[j]][e] * W[d][e] + b[d]      (12 x 1024)
__global__ void __launch_bounds__(256)
rows12_kernel(const float* __restrict__ emb, const float* __restrict__ W,
              const float* __restrict__ b, const int* __restrict__ idx,
              float* __restrict__ out) {
    int d = blockIdx.x;
    int t = threadIdx.x;
    int lane = t & 63;
    int q = t >> 6;
    int e0 = q * 256 + lane * 4;
    float4 w4 = *(const float4*)&W[(size_t)d * DIM + e0];
    float part[PICK];
#pragma unroll
    for (int j = 0; j < PICK; ++j) {
        int r = idx[j];
        float4 e4 = *(const float4*)&emb[(size_t)r * DIM + e0];
        part[j] = w4.x * e4.x + w4.y * e4.y + w4.z * e4.z + w4.w * e4.w;
    }
#pragma unroll
    for (int j = 0; j < PICK; ++j) {
        float v = part[j];
        for (int s = 32; s > 0; s >>= 1) v += __shfl_down(v, s, 64);
        part[j] = v;
    }
    __shared__ float red[4][PICK];
    if (lane == 0) {
#pragma unroll
        for (int j = 0; j < PICK; ++j) red[q][j] = part[j];
    }
    __syncthreads();
    if (t < PICK) {
        float s = red[0][t] + red[1][t] + red[2][t] + red[3][t] + b[d];
        out[t * DIM + d] = s;
    }
}

// TRANSPOSED output: out[j][e] += sum_d W[d][e] * V[j][d];  cvec[j] += sum_d b[d]*V[j][d]
__global__ void __launch_bounds__(256)
colmat_kernel(const float* __restrict__ W, const float* __restrict__ V,
              const float* __restrict__ b, float* __restrict__ out,
              float* __restrict__ cvec) {
    int blk = blockIdx.x;
    int t = threadIdx.x;
    if (blk == 128) {
        float part[PICK];
#pragma unroll
        for (int j = 0; j < PICK; ++j) part[j] = 0.f;
        for (int k = 0; k < 4; ++k) {
            int d = t + k * 256;
            float bv = b[d];
#pragma unroll
            for (int j = 0; j < PICK; ++j) part[j] += bv * V[j * DIM + d];
        }
#pragma unroll
        for (int j = 0; j < PICK; ++j) {
            float v = part[j];
            for (int s = 32; s > 0; s >>= 1) v += __shfl_down(v, s, 64);
            if ((t & 63) == 0) atomicAdd(&cvec[j], v);
        }
        return;
    }
    int eg = blk & 3;
    int dg = blk >> 2;
    int e = eg * 256 + t;
    int d0 = dg * 32;
    __shared__ float Vs[PICK][32];
    for (int i = t; i < PICK * 32; i += 256) {
        int j = i >> 5, dd = i & 31;
        Vs[j][dd] = V[j * DIM + d0 + dd];
    }
    __syncthreads();
    float acc[PICK];
#pragma unroll
    for (int j = 0; j < PICK; ++j) acc[j] = 0.f;
    for (int dd = 0; dd < 32; ++dd) {
        float w = W[(size_t)(d0 + dd) * DIM + e];
#pragma unroll
        for (int j = 0; j < PICK; ++j) acc[j] += w * Vs[j][dd];
    }
#pragma unroll
    for (int j = 0; j < PICK; ++j) atomicAdd(&out[j * DIM + e], acc[j]);
}

// -------------------------------------------------------------------------
// pass kernels (R10): 4-row tile, engineered under the 128-VGPR cap.
// R9 post-mortem: 8-row tile needed ~230 VGPRs; allocator capped at 128 and
// spilled ~100 regs -> 1.15 GB scratch WRITES per pass (vs 8 MB real),
// 790 us. Structure was correct (absmax 0.0) -- pure pressure failure.
// R10: amortize m-fragment LDS reads over 4 rows (DS-pipe occupancy
// 93% -> 57% of the HBM budget), holding m in QUARTERS of 3 j's so the
// whole kernel fits ~120 VGPRs even if the allocator repeats its 128 cap:
// acc[4][12]=48 + bufA/B=32 + m quarter=12 + addressing ~= 120.
// Same summation order as R8/R9 (chunk-major acc -> quad butterfly ->
// 16-quad sum): bit-identical numerics. Same scr epilogue (<=2-way LDS
// access, free), same 4x1KB wave-contiguous ping-pong prefetch.
// -------------------------------------------------------------------------

// one 256-col chunk for 4 rows: prefetch NBUF (4 rows, chunk PF_CHUNK of
// rows PF_ROW..), m fragments in quarters of 3, FMA CBUF into acc[4][12]
#define CHUNK4(CBUF, NBUF, CC, PF_ROW, PF_CHUNK)                              \
  {                                                                           \
    _Pragma("unroll") for (int r = 0; r < 4; ++r)                             \
      NBUF[r] = *(const float4*)(emb + (size_t)((PF_ROW) + r) * DIM +         \
                                 (PF_CHUNK) * 256 + l * 4);                   \
    _Pragma("unroll") for (int jq = 0; jq < 4; ++jq) {                        \
      float4 m0 = *(const float4*)&sMt[(3 * jq + 0) * DIM + (CC) * 256 + l * 4]; \
      float4 m1 = *(const float4*)&sMt[(3 * jq + 1) * DIM + (CC) * 256 + l * 4]; \
      float4 m2 = *(const float4*)&sMt[(3 * jq + 2) * DIM + (CC) * 256 + l * 4]; \
      _Pragma("unroll") for (int r = 0; r < 4; ++r) {                         \
        float4 vv = CBUF[r];                                                  \
        acc[r][3 * jq + 0] += vv.x * m0.x + vv.y * m0.y + vv.z * m0.z +       \
                              vv.w * m0.w;                                    \
        acc[r][3 * jq + 1] += vv.x * m1.x + vv.y * m1.y + vv.z * m1.z +       \
                              vv.w * m1.w;                                    \
        acc[r][3 * jq + 2] += vv.x * m2.x + vv.y * m2.y + vv.z * m2.z +       \
                              vv.w * m2.w;                                    \
      }                                                                       \
    }                                                                         \
  }

// epilogue for rows R0, R0+1 (acc indices): quad butterfly -> scr -> sum16
// -> +bias -> max butterfly. Lanes p=0/1 end with rows R0/R0+1 max.
#define EPI(R0, PAR, SINK)                                                    \
  {                                                                           \
    float a0[PICK], a1[PICK];                                                 \
    _Pragma("unroll") for (int j = 0; j < PICK; ++j) {                        \
      float v0 = acc[R0][j], v1 = acc[R0 + 1][j];                             \
      v0 += __shfl_xor(v0, 1, 64); v0 += __shfl_xor(v0, 2, 64);               \
      v1 += __shfl_xor(v1, 1, 64); v1 += __shfl_xor(v1, 2, 64);               \
      a0[j] = v0; a1[j] = v1;                                                 \
    }                                                                         \
    if ((l & 3) == 0) {                                                       \
      _Pragma("unroll") for (int jh = 0; jh < 6; ++jh) {                      \
        float4 b4 = {a0[2 * jh], a1[2 * jh], a0[2 * jh + 1], a1[2 * jh + 1]}; \
        *(float4*)&scr[PAR][w][q][jh * 4] = b4;                               \
      }                                                                       \
    }                                                                         \
    asm volatile("s_waitcnt lgkmcnt(0)" ::: "memory");                        \
    float sum = 0.f;                                                          \
    _Pragma("unroll") for (int qq = 0; qq < 16; ++qq)                         \
      sum += scr[PAR][w][qq][pidx];                                           \
    float vmax = (p < 24) ? sum + cb : -3e38f;                                \
    _Pragma("unroll") for (int mm = 2; mm <= 16; mm <<= 1)                    \
      vmax = fmaxf(vmax, __shfl_xor(vmax, mm, 64));                           \
    if (p < 2) SINK = vmax;                                                   \
  }

__global__ void __launch_bounds__(256, 2)
pass1_kernel(const float* __restrict__ emb, const float* __restrict__ Mt,
             const float* __restrict__ c0, float* __restrict__ maxv) {
    __shared__ __align__(16) float sMt[PICK * DIM];        // 48 KB
    __shared__ __align__(16) float scr[2][4][16][28];      // 14 KB
    int t = threadIdx.x;
    for (int i = t; i < PICK * DIM / 4; i += 256)
        ((float4*)sMt)[i] = ((const float4*)Mt)[i];
    __syncthreads();

    int l = t & 63, w = t >> 6;
    int q = l >> 2;
    int p = l;                       // pair id: p = j*2 + r for p < 24
    int pidx = (p < 24) ? p : 0;     // broadcast-read for idle lanes
    float cb = (p < 24) ? c0[p >> 1] : 0.f;
    size_t wrow = (size_t)blockIdx.x * 128 + (size_t)w * 32;

    float4 bufA[4], bufB[4];
#pragma unroll
    for (int r = 0; r < 4; ++r)
        bufA[r] = *(const float4*)(emb + (wrow + r) * DIM + l * 4);

    for (int tile = 0; tile < 8; ++tile) {
        size_t trow = wrow + (size_t)tile * 4;
        size_t ntrow = wrow + (size_t)((tile < 7) ? tile + 1 : 7) * 4;
        float acc[4][PICK];
#pragma unroll
        for (int r = 0; r < 4; ++r)
#pragma unroll
            for (int j = 0; j < PICK; ++j) acc[r][j] = 0.f;

        CHUNK4(bufA, bufB, 0, trow, 1);
        CHUNK4(bufB, bufA, 1, trow, 2);
        CHUNK4(bufA, bufB, 2, trow, 3);
        CHUNK4(bufB, bufA, 3, ntrow, 0);

        EPI(0, 0, maxv[trow + 0 + p]);
        EPI(2, 1, maxv[trow + 2 + p]);
    }
}

__global__ void __launch_bounds__(256, 2)
pass2_kernel(const float* __restrict__ emb, const float* __restrict__ Rt,
             const float* __restrict__ c1, float* __restrict__ out) {
    __shared__ __align__(16) float sMt[PICK * DIM];        // 48 KB
    __shared__ __align__(16) float scr[2][4][16][28];      // 14 KB
    __shared__ float pooled[128];
    int t = threadIdx.x;
    for (int i = t; i < PICK * DIM / 4; i += 256)
        ((float4*)sMt)[i] = ((const float4*)Rt)[i];
    __syncthreads();

    int l = t & 63, w = t >> 6;
    int q = l >> 2;
    int p = l;
    int pidx = (p < 24) ? p : 0;
    float cb = (p < 24) ? c1[p >> 1] : 0.f;
    size_t bbase = (size_t)blockIdx.x * 128;
    size_t wrow = bbase + (size_t)w * 32;

    float4 bufA[4], bufB[4];
#pragma unroll
    for (int r = 0; r < 4; ++r)
        bufA[r] = *(const float4*)(emb + (wrow + r) * DIM + l * 4);

    for (int tile = 0; tile < 8; ++tile) {
        size_t trow = wrow + (size_t)tile * 4;
        size_t ntrow = wrow + (size_t)((tile < 7) ? tile + 1 : 7) * 4;
        float acc[4][PICK];
#pragma unroll
        for (int r = 0; r < 4; ++r)
#pragma unroll
            for (int j = 0; j < PICK; ++j) acc[r][j] = 0.f;

        CHUNK4(bufA, bufB, 0, trow, 1);
        CHUNK4(bufB, bufA, 1, trow, 2);
        CHUNK4(bufA, bufB, 2, trow, 3);
        CHUNK4(bufB, bufA, 3, ntrow, 0);

        EPI(0, 0, pooled[w * 32 + tile * 4 + 0 + p]);
        EPI(2, 1, pooled[w * 32 + tile * 4 + 2 + p]);
    }
    __syncthreads();

    // phase B: thread t owns cols t*4..t*4+3; wave reads are 1 KB contiguous.
    // Re-walk the block's 128 rows (L2/L3-hot from phase A).
    const float* tp = emb + bbase * DIM + t * 4;
    float4 o = {0.f, 0.f, 0.f, 0.f};
#pragma unroll 8
    for (int r = 0; r < 128; ++r) {
        float pv = pooled[r];
        float4 v = *(const float4*)(tp + (size_t)r * DIM);
        o.x += pv * v.x; o.y += pv * v.y; o.z += pv * v.z; o.w += pv * v.w;
    }
    atomicAdd(&out[t * 4 + 0], o.x);
    atomicAdd(&out[t * 4 + 1], o.y);
    atomicAdd(&out[t * 4 + 2], o.z);
    atomicAdd(&out[t * 4 + 3], o.w);
}

// local top-12 of each 1024-chunk of maxv, single wave, register-resident,
// barrier-free: element q*64+t is only ever scanned AND cleared by lane t.
__global__ void __launch_bounds__(64)
top12_local(const float* __restrict__ maxv, float* __restrict__ cand_v,
            int* __restrict__ cand_i) {
    int t = threadIdx.x;
    int base = blockIdx.x * 1024;
    float lv[16];
#pragma unroll
    for (int q = 0; q < 16; ++q) lv[q] = maxv[base + q * 64 + t];
    for (int k = 0; k < PICK; ++k) {
        float bv = -3e38f; int bi = 0x7fffffff;
#pragma unroll
        for (int q = 0; q < 16; ++q) {
            int ii = base + q * 64 + t;
            float v = lv[q];
            if (v > bv || (v == bv && ii < bi)) { bv = v; bi = ii; }
        }
#pragma unroll
        for (int sft = 1; sft < 64; sft <<= 1) {
            float ov = __shfl_xor(bv, sft, 64);
            int oi = __shfl_xor(bi, sft, 64);
            if (ov > bv || (ov == bv && oi < bi)) { bv = ov; bi = oi; }
        }
        if (t == 0) {
            cand_v[blockIdx.x * PICK + k] = bv;
            cand_i[blockIdx.x * PICK + k] = bi;
        }
#pragma unroll
        for (int q = 0; q < 16; ++q)
            if (base + q * 64 + t == bi) lv[q] = -3e38f;
    }
}

// merge 768 candidates -> global top-12 indices; single wave, 12 regs/lane.
__global__ void __launch_bounds__(64)
top12_merge(const float* __restrict__ cand_v, const int* __restrict__ cand_i,
            int* __restrict__ top_idx) {
    int t = threadIdx.x;
    float lv[12]; int li[12];
#pragma unroll
    for (int q = 0; q < 12; ++q) {
        lv[q] = cand_v[q * 64 + t];
        li[q] = cand_i[q * 64 + t];
    }
    for (int k = 0; k < PICK; ++k) {
        float bv = -3e38f; int bi = 0x7fffffff; int bs = -1;
#pragma unroll
        for (int q = 0; q < 12; ++q) {
            if (lv[q] > bv || (lv[q] == bv && li[q] < bi)) {
                bv = lv[q]; bi = li[q]; bs = q * 64 + t;
            }
        }
#pragma unroll
        for (int sft = 1; sft < 64; sft <<= 1) {
            float ov = __shfl_xor(bv, sft, 64);
            int oi = __shfl_xor(bi, sft, 64);
            int os = __shfl_xor(bs, sft, 64);
            if (ov > bv || (ov == bv && oi < bi)) { bv = ov; bi = oi; bs = os; }
        }
        if (t == 0) top_idx[k] = bi;
#pragma unroll
        for (int q = 0; q < 12; ++q)
            if (q * 64 + t == bs) lv[q] = -3e38f;
    }
}

extern "C" void kernel_launch(void* const* d_in, const int* in_sizes, int n_in,
                              void* d_out, int out_size, void* d_ws, size_t ws_size,
                              hipStream_t stream) {
    const float* emb = (const float*)d_in[0];
    const float* Wq  = (const float*)d_in[1];
    const float* bq  = (const float*)d_in[2];
    const float* Wk  = (const float*)d_in[3];
    const float* bk  = (const float*)d_in[4];
    const int* indices = (const int*)d_in[5];
    float* out = (float*)d_out;
    float* ws = (float*)d_ws;

    float* NK      = ws;             // 12288
    float* Qr      = ws + 12288;     // 12288
    float* Mt      = ws + 24576;     // 12288 (zeroed, transposed [12][1024])
    float* Rt      = ws + 36864;     // 12288 (zeroed, transposed [12][1024])
    float* c0      = ws + 49152;     // 16    (zeroed)
    float* c1      = ws + 49168;     // 16    (zeroed)
    float* cand_v  = ws + 49184;     // 768
    int*   cand_i  = (int*)(ws + 49952);   // 768
    int*   top_idx = (int*)(ws + 50720);   // 16
    float* maxv    = ws + 50736;     // 65536

    hipMemsetAsync(Mt, 0, (size_t)(12288 * 2 + 32) * sizeof(float), stream);
    hipMemsetAsync(out, 0, DIM * sizeof(float), stream);

    rows12_kernel<<<1024, 256, 0, stream>>>(emb, Wk, bk, indices, NK);
    colmat_kernel<<<129, 256, 0, stream>>>(Wq, NK, bq, Mt, c0);
    pass1_kernel<<<512, 256, 0, stream>>>(emb, Mt, c0, maxv);
    top12_local<<<64, 64, 0, stream>>>(maxv, cand_v, cand_i);
    top12_merge<<<1, 64, 0, stream>>>(cand_v, cand_i, top_idx);
    rows12_kernel<<<1024, 256, 0, stream>>>(emb, Wq, bq, top_idx, Qr);
    colmat_kernel<<<129, 256, 0, stream>>>(Wk, Qr, bk, Rt, c1);
    pass2_kernel<<<512, 256, 0, stream>>>(emb, Rt, c1, out);
}

// Round 6
// 610.689 us; speedup vs baseline: 3.0914x; 1.3004x over previous
//
#include <hip/hip_runtime.h>

#define DIM 1024
#define NROWS 65536
#define PICK 12

// -------------------------------------------------------------------------
// ws layout (floats):
//   0      NK  [12][1024]
//   12288  Qr  [12][1024]
//   24576  Mt  [12][1024]   (zeroed, atomic-accumulated, TRANSPOSED: [j][e])
//   36864  Rt  [12][1024]   (zeroed, atomic-accumulated, TRANSPOSED: [j][e])
//   49152  c0  [12] (pad16, zeroed)
//   49168  c1  [12] (pad16, zeroed)
//   49184  cand_v [768]
//   49952  cand_i [768] (int)
//   50720  top_idx [12] (int, pad16)
//   50736  maxv [65536]
// -------------------------------------------------------------------------

// out[j][d] = sum_e emb[idx[j]][e] * W[d][e] + b[d]      (12 x 1024)
__global__ void __launch_bounds__(256)
rows12_kernel(const float* __restrict__ emb, const float* __restrict__ W,
              const float* __restrict__ b, const int* __restrict__ idx,
              float* __restrict__ out) {
    int d = blockIdx.x;
    int t = threadIdx.x;
    int lane = t & 63;
    int q = t >> 6;
    int e0 = q * 256 + lane * 4;
    float4 w4 = *(const float4*)&W[(size_t)d * DIM + e0];
    float part[PICK];
#pragma unroll
    for (int j = 0; j < PICK; ++j) {
        int r = idx[j];
        float4 e4 = *(const float4*)&emb[(size_t)r * DIM + e0];
        part[j] = w4.x * e4.x + w4.y * e4.y + w4.z * e4.z + w4.w * e4.w;
    }
#pragma unroll
    for (int j = 0; j < PICK; ++j) {
        float v = part[j];
        for (int s = 32; s > 0; s >>= 1) v += __shfl_down(v, s, 64);
        part[j] = v;
    }
    __shared__ float red[4][PICK];
    if (lane == 0) {
#pragma unroll
        for (int j = 0; j < PICK; ++j) red[q][j] = part[j];
    }
    __syncthreads();
    if (t < PICK) {
        float s = red[0][t] + red[1][t] + red[2][t] + red[3][t] + b[d];
        out[t * DIM + d] = s;
    }
}

// TRANSPOSED output: out[j][e] += sum_d W[d][e] * V[j][d];  cvec[j] += sum_d b[d]*V[j][d]
__global__ void __launch_bounds__(256)
colmat_kernel(const float* __restrict__ W, const float* __restrict__ V,
              const float* __restrict__ b, float* __restrict__ out,
              float* __restrict__ cvec) {
    int blk = blockIdx.x;
    int t = threadIdx.x;
    if (blk == 128) {
        float part[PICK];
#pragma unroll
        for (int j = 0; j < PICK; ++j) part[j] = 0.f;
        for (int k = 0; k < 4; ++k) {
            int d = t + k * 256;
            float bv = b[d];
#pragma unroll
            for (int j = 0; j < PICK; ++j) part[j] += bv * V[j * DIM + d];
        }
#pragma unroll
        for (int j = 0; j < PICK; ++j) {
            float v = part[j];
            for (int s = 32; s > 0; s >>= 1) v += __shfl_down(v, s, 64);
            if ((t & 63) == 0) atomicAdd(&cvec[j], v);
        }
        return;
    }
    int eg = blk & 3;
    int dg = blk >> 2;
    int e = eg * 256 + t;
    int d0 = dg * 32;
    __shared__ float Vs[PICK][32];
    for (int i = t; i < PICK * 32; i += 256) {
        int j = i >> 5, dd = i & 31;
        Vs[j][dd] = V[j * DIM + d0 + dd];
    }
    __syncthreads();
    float acc[PICK];
#pragma unroll
    for (int j = 0; j < PICK; ++j) acc[j] = 0.f;
    for (int dd = 0; dd < 32; ++dd) {
        float w = W[(size_t)(d0 + dd) * DIM + e];
#pragma unroll
        for (int j = 0; j < PICK; ++j) acc[j] += w * Vs[j][dd];
    }
#pragma unroll
    for (int j = 0; j < PICK; ++j) atomicAdd(&out[j * DIM + e], acc[j]);
}

// -------------------------------------------------------------------------
// pass kernels (R11): kill the spill.
// R10 post-mortem: VGPR_Count pinned at exactly 128 again (both R9 and R10
// used __launch_bounds__(256,2)) with 333 MB of spill WRITES (vs 0.3 MB
// real output); spill reads hit L2, dirty lines wash to HBM. Kernel was
// paced by its own scratch traffic at ~2.7 TB/s mixed R/W.
// R11, two register levers:
//  1. __launch_bounds__(256) -- no min-waves attr. 2 blocks/CU is already
//     guaranteed by LDS (62 KB); the attr only capped the allocator at 128.
//  2. Diet: in-place EPI butterflies (no a0/a1 copies, -24 regs); per-tile
//     row pointers so chunk offsets are 1024B immediates; no cross-tile
//     prefetch (one exposed load per tile; 8 waves/CU TLP covers it --
//     R3/R8 proved explicit pipelining buys nothing here).
// Peak live ~ acc48 + bufA16 + bufB16 + rp8 + m12 + temps ~= 115.
// Same summation order as R8-R10 (chunk-major acc -> quad butterfly ->
// 16-quad sum -> bias -> max butterfly): same numerics class.
// -------------------------------------------------------------------------

// one 256-col chunk for 4 rows: optional prefetch of chunk PFC into NBUF
// (immediate offsets off rp[]), m fragments in quarters of 3 j's,
// FMA CBUF into acc[4][12]
#define CHUNK4(CBUF, NBUF, CC, PFC, DOPF)                                     \
  {                                                                           \
    if (DOPF) {                                                               \
      _Pragma("unroll") for (int r = 0; r < 4; ++r)                           \
        NBUF[r] = *(const float4*)(rp[r] + (PFC) * 256);                      \
    }                                                                         \
    _Pragma("unroll") for (int jq = 0; jq < 4; ++jq) {                        \
      float4 m0 = *(const float4*)&sMt[(3 * jq + 0) * DIM + (CC) * 256 + l * 4]; \
      float4 m1 = *(const float4*)&sMt[(3 * jq + 1) * DIM + (CC) * 256 + l * 4]; \
      float4 m2 = *(const float4*)&sMt[(3 * jq + 2) * DIM + (CC) * 256 + l * 4]; \
      _Pragma("unroll") for (int r = 0; r < 4; ++r) {                         \
        float4 vv = CBUF[r];                                                  \
        acc[r][3 * jq + 0] += vv.x * m0.x + vv.y * m0.y + vv.z * m0.z +       \
                              vv.w * m0.w;                                    \
        acc[r][3 * jq + 1] += vv.x * m1.x + vv.y * m1.y + vv.z * m1.z +       \
                              vv.w * m1.w;                                    \
        acc[r][3 * jq + 2] += vv.x * m2.x + vv.y * m2.y + vv.z * m2.z +       \
                              vv.w * m2.w;                                    \
      }                                                                       \
    }                                                                         \
  }

// epilogue for rows R0, R0+1 (acc indices), in place: quad butterfly ->
// scr -> sum16 -> +bias -> max butterfly. Lanes p=0/1 end with the two maxes.
#define EPI(R0, PAR, SINK)                                                    \
  {                                                                           \
    _Pragma("unroll") for (int j = 0; j < PICK; ++j) {                        \
      float v0 = acc[R0][j], v1 = acc[R0 + 1][j];                             \
      v0 += __shfl_xor(v0, 1, 64); v0 += __shfl_xor(v0, 2, 64);               \
      v1 += __shfl_xor(v1, 1, 64); v1 += __shfl_xor(v1, 2, 64);               \
      acc[R0][j] = v0; acc[R0 + 1][j] = v1;                                   \
    }                                                                         \
    if ((l & 3) == 0) {                                                       \
      _Pragma("unroll") for (int jh = 0; jh < 6; ++jh) {                      \
        float4 b4 = {acc[R0][2 * jh], acc[R0 + 1][2 * jh],                    \
                     acc[R0][2 * jh + 1], acc[R0 + 1][2 * jh + 1]};           \
        *(float4*)&scr[PAR][w][q][jh * 4] = b4;                               \
      }                                                                       \
    }                                                                         \
    asm volatile("s_waitcnt lgkmcnt(0)" ::: "memory");                        \
    float sum = 0.f;                                                          \
    _Pragma("unroll") for (int qq = 0; qq < 16; ++qq)                         \
      sum += scr[PAR][w][qq][pidx];                                           \
    float vmax = (p < 24) ? sum + cb : -3e38f;                                \
    _Pragma("unroll") for (int mm = 2; mm <= 16; mm <<= 1)                    \
      vmax = fmaxf(vmax, __shfl_xor(vmax, mm, 64));                           \
    if (p < 2) SINK = vmax;                                                   \
  }

__global__ void __launch_bounds__(256)
pass1_kernel(const float* __restrict__ emb, const float* __restrict__ Mt,
             const float* __restrict__ c0, float* __restrict__ maxv) {
    __shared__ __align__(16) float sMt[PICK * DIM];        // 48 KB
    __shared__ __align__(16) float scr[2][4][16][28];      // 14 KB
    int t = threadIdx.x;
    for (int i = t; i < PICK * DIM / 4; i += 256)
        ((float4*)sMt)[i] = ((const float4*)Mt)[i];
    __syncthreads();

    int l = t & 63, w = t >> 6;
    int q = l >> 2;
    int p = l;                       // pair id: p = j*2 + r for p < 24
    int pidx = (p < 24) ? p : 0;     // broadcast-read for idle lanes
    float cb = (p < 24) ? c0[p >> 1] : 0.f;
    size_t wrow = (size_t)blockIdx.x * 128 + (size_t)w * 32;

    for (int tile = 0; tile < 8; ++tile) {
        size_t trow = wrow + (size_t)tile * 4;
        const float* rp[4];
#pragma unroll
        for (int r = 0; r < 4; ++r) rp[r] = emb + (trow + r) * DIM + l * 4;

        float4 bufA[4], bufB[4];
#pragma unroll
        for (int r = 0; r < 4; ++r) bufA[r] = *(const float4*)rp[r];

        float acc[4][PICK];
#pragma unroll
        for (int r = 0; r < 4; ++r)
#pragma unroll
            for (int j = 0; j < PICK; ++j) acc[r][j] = 0.f;

        CHUNK4(bufA, bufB, 0, 1, 1);
        CHUNK4(bufB, bufA, 1, 2, 1);
        CHUNK4(bufA, bufB, 2, 3, 1);
        CHUNK4(bufB, bufA, 3, 0, 0);

        EPI(0, 0, maxv[trow + 0 + p]);
        EPI(2, 1, maxv[trow + 2 + p]);
    }
}

__global__ void __launch_bounds__(256)
pass2_kernel(const float* __restrict__ emb, const float* __restrict__ Rt,
             const float* __restrict__ c1, float* __restrict__ out) {
    __shared__ __align__(16) float sMt[PICK * DIM];        // 48 KB
    __shared__ __align__(16) float scr[2][4][16][28];      // 14 KB
    __shared__ float pooled[128];
    int t = threadIdx.x;
    for (int i = t; i < PICK * DIM / 4; i += 256)
        ((float4*)sMt)[i] = ((const float4*)Rt)[i];
    __syncthreads();

    int l = t & 63, w = t >> 6;
    int q = l >> 2;
    int p = l;
    int pidx = (p < 24) ? p : 0;
    float cb = (p < 24) ? c1[p >> 1] : 0.f;
    size_t bbase = (size_t)blockIdx.x * 128;
    size_t wrow = bbase + (size_t)w * 32;

    for (int tile = 0; tile < 8; ++tile) {
        size_t trow = wrow + (size_t)tile * 4;
        const float* rp[4];
#pragma unroll
        for (int r = 0; r < 4; ++r) rp[r] = emb + (trow + r) * DIM + l * 4;

        float4 bufA[4], bufB[4];
#pragma unroll
        for (int r = 0; r < 4; ++r) bufA[r] = *(const float4*)rp[r];

        float acc[4][PICK];
#pragma unroll
        for (int r = 0; r < 4; ++r)
#pragma unroll
            for (int j = 0; j < PICK; ++j) acc[r][j] = 0.f;

        CHUNK4(bufA, bufB, 0, 1, 1);
        CHUNK4(bufB, bufA, 1, 2, 1);
        CHUNK4(bufA, bufB, 2, 3, 1);
        CHUNK4(bufB, bufA, 3, 0, 0);

        EPI(0, 0, pooled[w * 32 + tile * 4 + 0 + p]);
        EPI(2, 1, pooled[w * 32 + tile * 4 + 2 + p]);
    }
    __syncthreads();

    // phase B: thread t owns cols t*4..t*4+3; wave reads are 1 KB contiguous.
    // Re-walk the block's 128 rows (L2/L3-hot from phase A).
    const float* tp = emb + bbase * DIM + t * 4;
    float4 o = {0.f, 0.f, 0.f, 0.f};
#pragma unroll 8
    for (int r = 0; r < 128; ++r) {
        float pv = pooled[r];
        float4 v = *(const float4*)(tp + (size_t)r * DIM);
        o.x += pv * v.x; o.y += pv * v.y; o.z += pv * v.z; o.w += pv * v.w;
    }
    atomicAdd(&out[t * 4 + 0], o.x);
    atomicAdd(&out[t * 4 + 1], o.y);
    atomicAdd(&out[t * 4 + 2], o.z);
    atomicAdd(&out[t * 4 + 3], o.w);
}

// local top-12 of each 1024-chunk of maxv, single wave, register-resident,
// barrier-free: element q*64+t is only ever scanned AND cleared by lane t.
__global__ void __launch_bounds__(64)
top12_local(const float* __restrict__ maxv, float* __restrict__ cand_v,
            int* __restrict__ cand_i) {
    int t = threadIdx.x;
    int base = blockIdx.x * 1024;
    float lv[16];
#pragma unroll
    for (int q = 0; q < 16; ++q) lv[q] = maxv[base + q * 64 + t];
    for (int k = 0; k < PICK; ++k) {
        float bv = -3e38f; int bi = 0x7fffffff;
#pragma unroll
        for (int q = 0; q < 16; ++q) {
            int ii = base + q * 64 + t;
            float v = lv[q];
            if (v > bv || (v == bv && ii < bi)) { bv = v; bi = ii; }
        }
#pragma unroll
        for (int sft = 1; sft < 64; sft <<= 1) {
            float ov = __shfl_xor(bv, sft, 64);
            int oi = __shfl_xor(bi, sft, 64);
            if (ov > bv || (ov == bv && oi < bi)) { bv = ov; bi = oi; }
        }
        if (t == 0) {
            cand_v[blockIdx.x * PICK + k] = bv;
            cand_i[blockIdx.x * PICK + k] = bi;
        }
#pragma unroll
        for (int q = 0; q < 16; ++q)
            if (base + q * 64 + t == bi) lv[q] = -3e38f;
    }
}

// merge 768 candidates -> global top-12 indices; single wave, 12 regs/lane.
__global__ void __launch_bounds__(64)
top12_merge(const float* __restrict__ cand_v, const int* __restrict__ cand_i,
            int* __restrict__ top_idx) {
    int t = threadIdx.x;
    float lv[12]; int li[12];
#pragma unroll
    for (int q = 0; q < 12; ++q) {
        lv[q] = cand_v[q * 64 + t];
        li[q] = cand_i[q * 64 + t];
    }
    for (int k = 0; k < PICK; ++k) {
        float bv = -3e38f; int bi = 0x7fffffff; int bs = -1;
#pragma unroll
        for (int q = 0; q < 12; ++q) {
            if (lv[q] > bv || (lv[q] == bv && li[q] < bi)) {
                bv = lv[q]; bi = li[q]; bs = q * 64 + t;
            }
        }
#pragma unroll
        for (int sft = 1; sft < 64; sft <<= 1) {
            float ov = __shfl_xor(bv, sft, 64);
            int oi = __shfl_xor(bi, sft, 64);
            int os = __shfl_xor(bs, sft, 64);
            if (ov > bv || (ov == bv && oi < bi)) { bv = ov; bi = oi; bs = os; }
        }
        if (t == 0) top_idx[k] = bi;
#pragma unroll
        for (int q = 0; q < 12; ++q)
            if (q * 64 + t == bs) lv[q] = -3e38f;
    }
}

extern "C" void kernel_launch(void* const* d_in, const int* in_sizes, int n_in,
                              void* d_out, int out_size, void* d_ws, size_t ws_size,
                              hipStream_t stream) {
    const float* emb = (const float*)d_in[0];
    const float* Wq  = (const float*)d_in[1];
    const float* bq  = (const float*)d_in[2];
    const float* Wk  = (const float*)d_in[3];
    const float* bk  = (const float*)d_in[4];
    const int* indices = (const int*)d_in[5];
    float* out = (float*)d_out;
    float* ws = (float*)d_ws;

    float* NK      = ws;             // 12288
    float* Qr      = ws + 12288;     // 12288
    float* Mt      = ws + 24576;     // 12288 (zeroed, transposed [12][1024])
    float* Rt      = ws + 36864;     // 12288 (zeroed, transposed [12][1024])
    float* c0      = ws + 49152;     // 16    (zeroed)
    float* c1      = ws + 49168;     // 16    (zeroed)
    float* cand_v  = ws + 49184;     // 768
    int*   cand_i  = (int*)(ws + 49952);   // 768
    int*   top_idx = (int*)(ws + 50720);   // 16
    float* maxv    = ws + 50736;     // 65536

    hipMemsetAsync(Mt, 0, (size_t)(12288 * 2 + 32) * sizeof(float), stream);
    hipMemsetAsync(out, 0, DIM * sizeof(float), stream);

    rows12_kernel<<<1024, 256, 0, stream>>>(emb, Wk, bk, indices, NK);
    colmat_kernel<<<129, 256, 0, stream>>>(Wq, NK, bq, Mt, c0);
    pass1_kernel<<<512, 256, 0, stream>>>(emb, Mt, c0, maxv);
    top12_local<<<64, 64, 0, stream>>>(maxv, cand_v, cand_i);
    top12_merge<<<1, 64, 0, stream>>>(cand_v, cand_i, top_idx);
    rows12_kernel<<<1024, 256, 0, stream>>>(emb, Wq, bq, top_idx, Qr);
    colmat_kernel<<<129, 256, 0, stream>>>(Wk, Qr, bk, Rt, c1);
    pass2_kernel<<<512, 256, 0, stream>>>(emb, Rt, c1, out);
}

// Round 7
// 563.674 us; speedup vs baseline: 3.3493x; 1.0834x over previous
//
#include <hip/hip_runtime.h>

#define DIM 1024
#define NROWS 65536
#define PICK 12

// -------------------------------------------------------------------------
// ws layout (floats):
//   0      NK  [12][1024]
//   12288  Qr  [12][1024]
//   24576  Mt  [12][1024]   (zeroed, atomic-accumulated, TRANSPOSED: [j][e])
//   36864  Rt  [12][1024]   (zeroed, atomic-accumulated, TRANSPOSED: [j][e])
//   49152  c0  [12] (pad16, zeroed)
//   49168  c1  [12] (pad16, zeroed)
//   49184  cand_v [768]
//   49952  cand_i [768] (int)
//   50720  top_idx [12] (int, pad16)
//   50736  maxv [65536]
// -------------------------------------------------------------------------

// out[j][d] = sum_e emb[idx[j]][e] * W[d][e] + b[d]      (12 x 1024)
__global__ void __launch_bounds__(256)
rows12_kernel(const float* __restrict__ emb, const float* __restrict__ W,
              const float* __restrict__ b, const int* __restrict__ idx,
              float* __restrict__ out) {
    int d = blockIdx.x;
    int t = threadIdx.x;
    int lane = t & 63;
    int q = t >> 6;
    int e0 = q * 256 + lane * 4;
    float4 w4 = *(const float4*)&W[(size_t)d * DIM + e0];
    float part[PICK];
#pragma unroll
    for (int j = 0; j < PICK; ++j) {
        int r = idx[j];
        float4 e4 = *(const float4*)&emb[(size_t)r * DIM + e0];
        part[j] = w4.x * e4.x + w4.y * e4.y + w4.z * e4.z + w4.w * e4.w;
    }
#pragma unroll
    for (int j = 0; j < PICK; ++j) {
        float v = part[j];
        for (int s = 32; s > 0; s >>= 1) v += __shfl_down(v, s, 64);
        part[j] = v;
    }
    __shared__ float red[4][PICK];
    if (lane == 0) {
#pragma unroll
        for (int j = 0; j < PICK; ++j) red[q][j] = part[j];
    }
    __syncthreads();
    if (t < PICK) {
        float s = red[0][t] + red[1][t] + red[2][t] + red[3][t] + b[d];
        out[t * DIM + d] = s;
    }
}

// TRANSPOSED output: out[j][e] += sum_d W[d][e] * V[j][d];  cvec[j] += sum_d b[d]*V[j][d]
__global__ void __launch_bounds__(256)
colmat_kernel(const float* __restrict__ W, const float* __restrict__ V,
              const float* __restrict__ b, float* __restrict__ out,
              float* __restrict__ cvec) {
    int blk = blockIdx.x;
    int t = threadIdx.x;
    if (blk == 128) {
        float part[PICK];
#pragma unroll
        for (int j = 0; j < PICK; ++j) part[j] = 0.f;
        for (int k = 0; k < 4; ++k) {
            int d = t + k * 256;
            float bv = b[d];
#pragma unroll
            for (int j = 0; j < PICK; ++j) part[j] += bv * V[j * DIM + d];
        }
#pragma unroll
        for (int j = 0; j < PICK; ++j) {
            float v = part[j];
            for (int s = 32; s > 0; s >>= 1) v += __shfl_down(v, s, 64);
            if ((t & 63) == 0) atomicAdd(&cvec[j], v);
        }
        return;
    }
    int eg = blk & 3;
    int dg = blk >> 2;
    int e = eg * 256 + t;
    int d0 = dg * 32;
    __shared__ float Vs[PICK][32];
    for (int i = t; i < PICK * 32; i += 256) {
        int j = i >> 5, dd = i & 31;
        Vs[j][dd] = V[j * DIM + d0 + dd];
    }
    __syncthreads();
    float acc[PICK];
#pragma unroll
    for (int j = 0; j < PICK; ++j) acc[j] = 0.f;
    for (int dd = 0; dd < 32; ++dd) {
        float w = W[(size_t)(d0 + dd) * DIM + e];
#pragma unroll
        for (int j = 0; j < PICK; ++j) acc[j] += w * Vs[j][dd];
    }
#pragma unroll
    for (int j = 0; j < PICK; ++j) atomicAdd(&out[j * DIM + e], acc[j]);
}

// -------------------------------------------------------------------------
// pass kernels (R12): move the epilogue butterflies off the DS pipe.
// R11 post-mortem: __shfl_* compiles to DS instrs (ds_swizzle/bpermute)
// sharing the LDS pipe with the m-reads. DS audit of R8's 2-row PG:
// ~74 shfl/scr ops + 48 ds_read_b128 per 2 rows -> DS pipe ~92% of the
// HBM cycle budget, co-limiting. That explains every null so far.
// R12 combines the proven-best pieces:
//  - 4-row tile (m-read amortization, R10) + cross-tile ping-pong prefetch
//    (worth ~13 us/pass, R6-vs-R3 measurement).
//  - no min-waves launch-bounds attr + in-place EPI (R11, spill-free).
//  - NEW: quad butterflies via DPP quad_perm (v_mov_b32_dpp + v_add_f32 =
//    pure VALU, zero DS). Removes 96 of ~148 DS ops per 4-row tile; DS
//    drops to ~60% of HBM budget. VALU has headroom (11% busy).
// Numerics: DPP xor-1/xor-2 pairs sum in the same order as shfl_xor 1,2 --
// same result class as R8-R11.
// -------------------------------------------------------------------------

__device__ __forceinline__ float qadd1(float v) {   // v += lane^1 (quad_perm [1,0,3,2])
    return v + __int_as_float(__builtin_amdgcn_update_dpp(
        0, __float_as_int(v), 0xB1, 0xF, 0xF, true));
}
__device__ __forceinline__ float qadd2(float v) {   // v += lane^2 (quad_perm [2,3,0,1])
    return v + __int_as_float(__builtin_amdgcn_update_dpp(
        0, __float_as_int(v), 0x4E, 0xF, 0xF, true));
}
__device__ __forceinline__ float qmax2(float v) {   // v = max(v, lane^2)
    return fmaxf(v, __int_as_float(__builtin_amdgcn_update_dpp(
        0, __float_as_int(v), 0x4E, 0xF, 0xF, true)));
}

// one 256-col chunk for 4 rows: prefetch chunk PF_CHUNK of rows PF_ROW..
// into NBUF, m fragments in quarters of 3 j's, FMA CBUF into acc[4][12]
#define CHUNK4(CBUF, NBUF, CC, PF_ROW, PF_CHUNK)                              \
  {                                                                           \
    _Pragma("unroll") for (int r = 0; r < 4; ++r)                             \
      NBUF[r] = *(const float4*)(emb + (size_t)((PF_ROW) + r) * DIM +         \
                                 (PF_CHUNK) * 256 + l * 4);                   \
    _Pragma("unroll") for (int jq = 0; jq < 4; ++jq) {                        \
      float4 m0 = *(const float4*)&sMt[(3 * jq + 0) * DIM + (CC) * 256 + l * 4]; \
      float4 m1 = *(const float4*)&sMt[(3 * jq + 1) * DIM + (CC) * 256 + l * 4]; \
      float4 m2 = *(const float4*)&sMt[(3 * jq + 2) * DIM + (CC) * 256 + l * 4]; \
      _Pragma("unroll") for (int r = 0; r < 4; ++r) {                         \
        float4 vv = CBUF[r];                                                  \
        acc[r][3 * jq + 0] += vv.x * m0.x + vv.y * m0.y + vv.z * m0.z +       \
                              vv.w * m0.w;                                    \
        acc[r][3 * jq + 1] += vv.x * m1.x + vv.y * m1.y + vv.z * m1.z +       \
                              vv.w * m1.w;                                    \
        acc[r][3 * jq + 2] += vv.x * m2.x + vv.y * m2.y + vv.z * m2.z +       \
                              vv.w * m2.w;                                    \
      }                                                                       \
    }                                                                         \
  }

// epilogue for rows R0, R0+1 (acc indices), in place: DPP quad butterfly
// (VALU) -> scr -> sum16 -> +bias -> max butterfly (DPP for xor2, shfl for
// xor4/8/16). Lanes p=0/1 end with the two row maxes.
#define EPI(R0, PAR, SINK)                                                    \
  {                                                                           \
    _Pragma("unroll") for (int j = 0; j < PICK; ++j) {                        \
      acc[R0][j]     = qadd2(qadd1(acc[R0][j]));                              \
      acc[R0 + 1][j] = qadd2(qadd1(acc[R0 + 1][j]));                          \
    }                                                                         \
    if ((l & 3) == 0) {                                                       \
      _Pragma("unroll") for (int jh = 0; jh < 6; ++jh) {                      \
        float4 b4 = {acc[R0][2 * jh], acc[R0 + 1][2 * jh],                    \
                     acc[R0][2 * jh + 1], acc[R0 + 1][2 * jh + 1]};           \
        *(float4*)&scr[PAR][w][q][jh * 4] = b4;                               \
      }                                                                       \
    }                                                                         \
    asm volatile("s_waitcnt lgkmcnt(0)" ::: "memory");                        \
    float sum = 0.f;                                                          \
    _Pragma("unroll") for (int qq = 0; qq < 16; ++qq)                         \
      sum += scr[PAR][w][qq][pidx];                                           \
    float vmax = (p < 24) ? sum + cb : -3e38f;                                \
    vmax = qmax2(vmax);                                                       \
    vmax = fmaxf(vmax, __shfl_xor(vmax, 4, 64));                              \
    vmax = fmaxf(vmax, __shfl_xor(vmax, 8, 64));                              \
    vmax = fmaxf(vmax, __shfl_xor(vmax, 16, 64));                             \
    if (p < 2) SINK = vmax;                                                   \
  }

__global__ void __launch_bounds__(256)
pass1_kernel(const float* __restrict__ emb, const float* __restrict__ Mt,
             const float* __restrict__ c0, float* __restrict__ maxv) {
    __shared__ __align__(16) float sMt[PICK * DIM];        // 48 KB
    __shared__ __align__(16) float scr[2][4][16][28];      // 14 KB
    int t = threadIdx.x;
    for (int i = t; i < PICK * DIM / 4; i += 256)
        ((float4*)sMt)[i] = ((const float4*)Mt)[i];
    __syncthreads();

    int l = t & 63, w = t >> 6;
    int q = l >> 2;
    int p = l;                       // pair id: p = j*2 + r for p < 24
    int pidx = (p < 24) ? p : 0;     // broadcast-read for idle lanes
    float cb = (p < 24) ? c0[p >> 1] : 0.f;
    size_t wrow = (size_t)blockIdx.x * 128 + (size_t)w * 32;

    float4 bufA[4], bufB[4];
#pragma unroll
    for (int r = 0; r < 4; ++r)
        bufA[r] = *(const float4*)(emb + (wrow + r) * DIM + l * 4);

    for (int tile = 0; tile < 8; ++tile) {
        size_t trow = wrow + (size_t)tile * 4;
        size_t ntrow = wrow + (size_t)((tile < 7) ? tile + 1 : 7) * 4;
        float acc[4][PICK];
#pragma unroll
        for (int r = 0; r < 4; ++r)
#pragma unroll
            for (int j = 0; j < PICK; ++j) acc[r][j] = 0.f;

        CHUNK4(bufA, bufB, 0, trow, 1);
        CHUNK4(bufB, bufA, 1, trow, 2);
        CHUNK4(bufA, bufB, 2, trow, 3);
        CHUNK4(bufB, bufA, 3, ntrow, 0);

        EPI(0, 0, maxv[trow + 0 + p]);
        EPI(2, 1, maxv[trow + 2 + p]);
    }
}

__global__ void __launch_bounds__(256)
pass2_kernel(const float* __restrict__ emb, const float* __restrict__ Rt,
             const float* __restrict__ c1, float* __restrict__ out) {
    __shared__ __align__(16) float sMt[PICK * DIM];        // 48 KB
    __shared__ __align__(16) float scr[2][4][16][28];      // 14 KB
    __shared__ float pooled[128];
    int t = threadIdx.x;
    for (int i = t; i < PICK * DIM / 4; i += 256)
        ((float4*)sMt)[i] = ((const float4*)Rt)[i];
    __syncthreads();

    int l = t & 63, w = t >> 6;
    int q = l >> 2;
    int p = l;
    int pidx = (p < 24) ? p : 0;
    float cb = (p < 24) ? c1[p >> 1] : 0.f;
    size_t bbase = (size_t)blockIdx.x * 128;
    size_t wrow = bbase + (size_t)w * 32;

    float4 bufA[4], bufB[4];
#pragma unroll
    for (int r = 0; r < 4; ++r)
        bufA[r] = *(const float4*)(emb + (wrow + r) * DIM + l * 4);

    for (int tile = 0; tile < 8; ++tile) {
        size_t trow = wrow + (size_t)tile * 4;
        size_t ntrow = wrow + (size_t)((tile < 7) ? tile + 1 : 7) * 4;
        float acc[4][PICK];
#pragma unroll
        for (int r = 0; r < 4; ++r)
#pragma unroll
            for (int j = 0; j < PICK; ++j) acc[r][j] = 0.f;

        CHUNK4(bufA, bufB, 0, trow, 1);
        CHUNK4(bufB, bufA, 1, trow, 2);
        CHUNK4(bufA, bufB, 2, trow, 3);
        CHUNK4(bufB, bufA, 3, ntrow, 0);

        EPI(0, 0, pooled[w * 32 + tile * 4 + 0 + p]);
        EPI(2, 1, pooled[w * 32 + tile * 4 + 2 + p]);
    }
    __syncthreads();

    // phase B: thread t owns cols t*4..t*4+3; wave reads are 1 KB contiguous.
    // Re-walk the block's 128 rows (L2/L3-hot from phase A).
    const float* tp = emb + bbase * DIM + t * 4;
    float4 o = {0.f, 0.f, 0.f, 0.f};
#pragma unroll 8
    for (int r = 0; r < 128; ++r) {
        float pv = pooled[r];
        float4 v = *(const float4*)(tp + (size_t)r * DIM);
        o.x += pv * v.x; o.y += pv * v.y; o.z += pv * v.z; o.w += pv * v.w;
    }
    atomicAdd(&out[t * 4 + 0], o.x);
    atomicAdd(&out[t * 4 + 1], o.y);
    atomicAdd(&out[t * 4 + 2], o.z);
    atomicAdd(&out[t * 4 + 3], o.w);
}

// local top-12 of each 1024-chunk of maxv, single wave, register-resident,
// barrier-free: element q*64+t is only ever scanned AND cleared by lane t.
__global__ void __launch_bounds__(64)
top12_local(const float* __restrict__ maxv, float* __restrict__ cand_v,
            int* __restrict__ cand_i) {
    int t = threadIdx.x;
    int base = blockIdx.x * 1024;
    float lv[16];
#pragma unroll
    for (int q = 0; q < 16; ++q) lv[q] = maxv[base + q * 64 + t];
    for (int k = 0; k < PICK; ++k) {
        float bv = -3e38f; int bi = 0x7fffffff;
#pragma unroll
        for (int q = 0; q < 16; ++q) {
            int ii = base + q * 64 + t;
            float v = lv[q];
            if (v > bv || (v == bv && ii < bi)) { bv = v; bi = ii; }
        }
#pragma unroll
        for (int sft = 1; sft < 64; sft <<= 1) {
            float ov = __shfl_xor(bv, sft, 64);
            int oi = __shfl_xor(bi, sft, 64);
            if (ov > bv || (ov == bv && oi < bi)) { bv = ov; bi = oi; }
        }
        if (t == 0) {
            cand_v[blockIdx.x * PICK + k] = bv;
            cand_i[blockIdx.x * PICK + k] = bi;
        }
#pragma unroll
        for (int q = 0; q < 16; ++q)
            if (base + q * 64 + t == bi) lv[q] = -3e38f;
    }
}

// merge 768 candidates -> global top-12 indices; single wave, 12 regs/lane.
__global__ void __launch_bounds__(64)
top12_merge(const float* __restrict__ cand_v, const int* __restrict__ cand_i,
            int* __restrict__ top_idx) {
    int t = threadIdx.x;
    float lv[12]; int li[12];
#pragma unroll
    for (int q = 0; q < 12; ++q) {
        lv[q] = cand_v[q * 64 + t];
        li[q] = cand_i[q * 64 + t];
    }
    for (int k = 0; k < PICK; ++k) {
        float bv = -3e38f; int bi = 0x7fffffff; int bs = -1;
#pragma unroll
        for (int q = 0; q < 12; ++q) {
            if (lv[q] > bv || (lv[q] == bv && li[q] < bi)) {
                bv = lv[q]; bi = li[q]; bs = q * 64 + t;
            }
        }
#pragma unroll
        for (int sft = 1; sft < 64; sft <<= 1) {
            float ov = __shfl_xor(bv, sft, 64);
            int oi = __shfl_xor(bi, sft, 64);
            int os = __shfl_xor(bs, sft, 64);
            if (ov > bv || (ov == bv && oi < bi)) { bv = ov; bi = oi; bs = os; }
        }
        if (t == 0) top_idx[k] = bi;
#pragma unroll
        for (int q = 0; q < 12; ++q)
            if (q * 64 + t == bs) lv[q] = -3e38f;
    }
}

extern "C" void kernel_launch(void* const* d_in, const int* in_sizes, int n_in,
                              void* d_out, int out_size, void* d_ws, size_t ws_size,
                              hipStream_t stream) {
    const float* emb = (const float*)d_in[0];
    const float* Wq  = (const float*)d_in[1];
    const float* bq  = (const float*)d_in[2];
    const float* Wk  = (const float*)d_in[3];
    const float* bk  = (const float*)d_in[4];
    const int* indices = (const int*)d_in[5];
    float* out = (float*)d_out;
    float* ws = (float*)d_ws;

    float* NK      = ws;             // 12288
    float* Qr      = ws + 12288;     // 12288
    float* Mt      = ws + 24576;     // 12288 (zeroed, transposed [12][1024])
    float* Rt      = ws + 36864;     // 12288 (zeroed, transposed [12][1024])
    float* c0      = ws + 49152;     // 16    (zeroed)
    float* c1      = ws + 49168;     // 16    (zeroed)
    float* cand_v  = ws + 49184;     // 768
    int*   cand_i  = (int*)(ws + 49952);   // 768
    int*   top_idx = (int*)(ws + 50720);   // 16
    float* maxv    = ws + 50736;     // 65536

    hipMemsetAsync(Mt, 0, (size_t)(12288 * 2 + 32) * sizeof(float), stream);
    hipMemsetAsync(out, 0, DIM * sizeof(float), stream);

    rows12_kernel<<<1024, 256, 0, stream>>>(emb, Wk, bk, indices, NK);
    colmat_kernel<<<129, 256, 0, stream>>>(Wq, NK, bq, Mt, c0);
    pass1_kernel<<<512, 256, 0, stream>>>(emb, Mt, c0, maxv);
    top12_local<<<64, 64, 0, stream>>>(maxv, cand_v, cand_i);
    top12_merge<<<1, 64, 0, stream>>>(cand_v, cand_i, top_idx);
    rows12_kernel<<<1024, 256, 0, stream>>>(emb, Wq, bq, top_idx, Qr);
    colmat_kernel<<<129, 256, 0, stream>>>(Wk, Qr, bk, Rt, c1);
    pass2_kernel<<<512, 256, 0, stream>>>(emb, Rt, c1, out);
}